// Round 3
// baseline (704.396 us; speedup 1.0000x reference)
//
#include <hip/hip_runtime.h>
#include <hip/hip_bf16.h>

#define D 128
#define BM 64
#define BK 32
#define XS 66   // padded LDS stride for transposed x tile: stores 2-way (free), float2 reads aligned

__device__ __forceinline__ float bf2f(unsigned short v) {
    union { unsigned int u; float f; } t;
    t.u = ((unsigned int)v) << 16;
    return t.f;
}

// ---------------- combined degree count: grid.y = relation ----------------
__global__ void degree_all(const int* __restrict__ s0, const int* __restrict__ d0,
                           const int* __restrict__ s1, const int* __restrict__ d1,
                           const int* __restrict__ s2, const int* __restrict__ d2,
                           int* __restrict__ cnt, int N, int E) {
    int r = blockIdx.y;
    const int* src = (r == 0) ? s0 : (r == 1) ? s1 : s2;
    const int* dst = (r == 0) ? d0 : (r == 1) ? d1 : d2;
    int i = blockIdx.x * blockDim.x + threadIdx.x;
    if (i < E) {
        atomicAdd(&cnt[(size_t)r * N + src[i]], 1);               // out-degree block [0,3N)
        atomicAdd(&cnt[(size_t)3 * N + (size_t)r * N + dst[i]], 1); // in-degree block [3N,6N)
    }
}

// ---------------- cnt(int) -> rsqrt(max(cnt,1)) ----------------
__global__ void rsqrt_kernel(const int* __restrict__ cnt, float* __restrict__ rs, int n) {
    int i = blockIdx.x * blockDim.x + threadIdx.x;
    if (i < n) rs[i] = rsqrtf(fmaxf((float)cnt[i], 1.0f));
}

// ---------------- exclusive scan over 3N: phase 1 (per-block) ----------------
__global__ void scan_block(const int* __restrict__ in, int* __restrict__ out,
                           int* __restrict__ aux, int n) {
    __shared__ int tmp[256];
    int tid = threadIdx.x;
    int gid = blockIdx.x * 256 + tid;
    int v = (gid < n) ? in[gid] : 0;
    tmp[tid] = v;
    __syncthreads();
    for (int o = 1; o < 256; o <<= 1) {
        int t = (tid >= o) ? tmp[tid - o] : 0;
        __syncthreads();
        tmp[tid] += t;
        __syncthreads();
    }
    if (gid < n) out[gid] = tmp[tid] - v;   // exclusive
    if (tid == 255) aux[blockIdx.x] = tmp[255];
}

// ---------------- scan phase 2: single block, 1024 thr, 2 elems/thread (nb<=2048) ----------------
__global__ void scan_aux2(int* __restrict__ aux, int nb) {
    __shared__ int tmp[1024];
    int tid = threadIdx.x;
    int i0 = 2 * tid, i1 = 2 * tid + 1;
    int v0 = (i0 < nb) ? aux[i0] : 0;
    int v1 = (i1 < nb) ? aux[i1] : 0;
    int s = v0 + v1;
    tmp[tid] = s;
    __syncthreads();
    for (int o = 1; o < 1024; o <<= 1) {
        int t = (tid >= o) ? tmp[tid - o] : 0;
        __syncthreads();
        tmp[tid] += t;
        __syncthreads();
    }
    int excl = tmp[tid] - s;
    if (i0 < nb) aux[i0] = excl;
    if (i1 < nb) aux[i1] = excl + v0;
}

// ---------------- scan phase 3 (add block offsets) ----------------
__global__ void scan_add(int* __restrict__ out, const int* __restrict__ aux, int n) {
    int gid = blockIdx.x * 256 + threadIdx.x;
    if (gid < n) out[gid] += aux[blockIdx.x];
}

// ---------------- combined CSR fill: grid.y = relation ----------------
__global__ void fill_all(const int* __restrict__ s0, const int* __restrict__ d0,
                         const int* __restrict__ s1, const int* __restrict__ d1,
                         const int* __restrict__ s2, const int* __restrict__ d2,
                         const int* __restrict__ off, int* __restrict__ cursor,
                         int* __restrict__ srcs, int N, int E) {
    int r = blockIdx.y;
    const int* src = (r == 0) ? s0 : (r == 1) ? s1 : s2;
    const int* dst = (r == 0) ? d0 : (r == 1) ? d1 : d2;
    int e = blockIdx.x * blockDim.x + threadIdx.x;
    if (e >= E) return;
    int d = dst[e];
    size_t g = (size_t)r * N + d;
    int p = atomicAdd(&cursor[g], 1);
    srcs[off[g] + p] = src[e];
}

// ---------------- y = x @ W  (fp32 compute, bf16 store; prefetched, conflict-free) ----------------
__global__ __launch_bounds__(256) void gemm_kernel(const float* __restrict__ x,
                                                   const float* __restrict__ W,
                                                   __hip_bfloat16* __restrict__ y, int nrows) {
    __shared__ float xs[BK * XS];  // transposed x tile [k][row], stride 66
    __shared__ float ws[BK][D];    // W tile [k][col]

    const int tid = threadIdx.x;
    const int tx = tid & 31;   // cols tx*4 .. tx*4+3
    const int ty = tid >> 5;   // rows ty*8 .. ty*8+7
    const int row0 = blockIdx.x * BM;

    // staging index decomposition (constant per thread)
    const int xr0 = tid >> 3;          // x row for l=0 (0..31); l=1 adds 32
    const int xk4 = tid & 7;           // x float4-k index
    const int wk0 = tid >> 5;          // w k for l=0 (0..7); l adds 8
    const int wc4 = tid & 31;          // w float4-col index

    float acc[8][4];
#pragma unroll
    for (int i = 0; i < 8; ++i)
#pragma unroll
        for (int j = 0; j < 4; ++j) acc[i][j] = 0.f;

    float4 xv[2];
    float4 wv4[4];

    // prefetch kt=0
#pragma unroll
    for (int l = 0; l < 2; ++l) {
        int grow = row0 + xr0 + l * 32;
        xv[l] = (grow < nrows) ? *(const float4*)(x + (size_t)grow * D + xk4 * 4)
                               : make_float4(0.f, 0.f, 0.f, 0.f);
    }
#pragma unroll
    for (int l = 0; l < 4; ++l)
        wv4[l] = *(const float4*)(W + (size_t)(wk0 + l * 8) * D + wc4 * 4);

    for (int kt = 0; kt < D; kt += BK) {
        __syncthreads();
        // store staged tiles to LDS
#pragma unroll
        for (int l = 0; l < 2; ++l) {
            int r = xr0 + l * 32;
            xs[(xk4 * 4 + 0) * XS + r] = xv[l].x;
            xs[(xk4 * 4 + 1) * XS + r] = xv[l].y;
            xs[(xk4 * 4 + 2) * XS + r] = xv[l].z;
            xs[(xk4 * 4 + 3) * XS + r] = xv[l].w;
        }
#pragma unroll
        for (int l = 0; l < 4; ++l)
            *(float4*)&ws[wk0 + l * 8][wc4 * 4] = wv4[l];
        __syncthreads();
        // prefetch next k-tile (overlaps compute below)
        if (kt + BK < D) {
            int ktn = kt + BK;
#pragma unroll
            for (int l = 0; l < 2; ++l) {
                int grow = row0 + xr0 + l * 32;
                xv[l] = (grow < nrows) ? *(const float4*)(x + (size_t)grow * D + ktn + xk4 * 4)
                                       : make_float4(0.f, 0.f, 0.f, 0.f);
            }
#pragma unroll
            for (int l = 0; l < 4; ++l)
                wv4[l] = *(const float4*)(W + (size_t)(ktn + wk0 + l * 8) * D + wc4 * 4);
        }
#pragma unroll
        for (int k = 0; k < BK; ++k) {
            float4 wv = *(const float4*)&ws[k][tx * 4];
            const float* xr = &xs[k * XS + ty * 8];
            float2 p0 = *(const float2*)(xr);
            float2 p1 = *(const float2*)(xr + 2);
            float2 p2 = *(const float2*)(xr + 4);
            float2 p3 = *(const float2*)(xr + 6);
            float xv8[8] = {p0.x, p0.y, p1.x, p1.y, p2.x, p2.y, p3.x, p3.y};
#pragma unroll
            for (int i = 0; i < 8; ++i) {
                acc[i][0] += xv8[i] * wv.x;
                acc[i][1] += xv8[i] * wv.y;
                acc[i][2] += xv8[i] * wv.z;
                acc[i][3] += xv8[i] * wv.w;
            }
        }
    }
#pragma unroll
    for (int i = 0; i < 8; ++i) {
        int grow = row0 + ty * 8 + i;
        if (grow < nrows) {
            union { ushort4 u; __hip_bfloat16 h[4]; } pk;
            pk.h[0] = __float2bfloat16(acc[i][0]);
            pk.h[1] = __float2bfloat16(acc[i][1]);
            pk.h[2] = __float2bfloat16(acc[i][2]);
            pk.h[3] = __float2bfloat16(acc[i][3]);
            *(ushort4*)((unsigned short*)y + (size_t)grow * D + tx * 4) = pk.u;
        }
    }
}

// ---------------- gather-side aggregate: one 32-lane group per dst node ----------------
// MODE 0: out = acc*ri   1: out += acc*ri   2: out = relu(out + acc*ri + b0+b1+b2)
template <int MODE>
__global__ __launch_bounds__(256) void agg_kernel(const __hip_bfloat16* __restrict__ y,
                                                  const int* __restrict__ srcs,
                                                  const int* __restrict__ off,
                                                  const float* __restrict__ rs_out,
                                                  const float* __restrict__ rs_in,
                                                  const float* __restrict__ b0,
                                                  const float* __restrict__ b1,
                                                  const float* __restrict__ b2,
                                                  float* __restrict__ out,
                                                  int N, int rbase, int threeN, int Etot) {
    int gid  = blockIdx.x * blockDim.x + threadIdx.x;
    int node = gid >> 5;
    int lane = gid & 31;
    if (node >= N) return;
    int g = rbase + node;
    int j0 = off[g];
    int j1 = (g == threeN - 1) ? Etot : off[g + 1];

    float ri = rs_in[node];
    float a0 = 0.f, a1 = 0.f, a2 = 0.f, a3 = 0.f;
    for (int j = j0; j < j1; ++j) {
        int s = srcs[j];
        float c = rs_out[s];
        ushort4 u = *(const ushort4*)((const unsigned short*)y + (size_t)s * D + lane * 4);
        a0 += c * bf2f(u.x);
        a1 += c * bf2f(u.y);
        a2 += c * bf2f(u.z);
        a3 += c * bf2f(u.w);
    }
    float4 o = make_float4(a0 * ri, a1 * ri, a2 * ri, a3 * ri);
    float* orow = out + (size_t)node * D + lane * 4;
    if (MODE == 0) {
        *(float4*)orow = o;
    } else {
        float4 p = *(const float4*)orow;
        o.x += p.x; o.y += p.y; o.z += p.z; o.w += p.w;
        if (MODE == 2) {
            int c0 = lane * 4;
            o.x = fmaxf(o.x + b0[c0 + 0] + b1[c0 + 0] + b2[c0 + 0], 0.f);
            o.y = fmaxf(o.y + b0[c0 + 1] + b1[c0 + 1] + b2[c0 + 1], 0.f);
            o.z = fmaxf(o.z + b0[c0 + 2] + b1[c0 + 2] + b2[c0 + 2], 0.f);
            o.w = fmaxf(o.w + b0[c0 + 3] + b1[c0 + 3] + b2[c0 + 3], 0.f);
        }
        *(float4*)orow = o;
    }
}

extern "C" void kernel_launch(void* const* d_in, const int* in_sizes, int n_in,
                              void* d_out, int out_size, void* d_ws, size_t ws_size,
                              hipStream_t stream) {
    const float* x = (const float*)d_in[0];
    const float* W[3]   = {(const float*)d_in[1], (const float*)d_in[5], (const float*)d_in[9]};
    const float* b[3]   = {(const float*)d_in[2], (const float*)d_in[6], (const float*)d_in[10]};
    const int*   src[3] = {(const int*)d_in[3],   (const int*)d_in[7],   (const int*)d_in[11]};
    const int*   dst[3] = {(const int*)d_in[4],   (const int*)d_in[8],   (const int*)d_in[12]};

    const int N = in_sizes[0] / D;
    const int E = in_sizes[3];
    const int threeN = 3 * N;
    const int Etot = 3 * E;
    float* out = (float*)d_out;

    // ws: [cnt 6N int][cursor 3N int][rs 6N f][off 3N int][aux 2048 int][srcs 3E int][y N*D bf16] ~40MB
    char* p = (char*)d_ws;
    int* cnt    = (int*)p;   p += (size_t)6 * N * 4;   // [0,3N)=out-deg by rel, [3N,6N)=in-deg
    int* cursor = (int*)p;   p += (size_t)3 * N * 4;
    float* rs   = (float*)p; p += (size_t)6 * N * 4;   // same layout as cnt
    int* off    = (int*)p;   p += (size_t)3 * N * 4;
    int* aux    = (int*)p;   p += (size_t)2048 * 4;
    int* srcs   = (int*)p;   p += (size_t)Etot * 4;
    p = (char*)(((uintptr_t)p + 15) & ~(uintptr_t)15);
    __hip_bfloat16* y = (__hip_bfloat16*)p;

    hipMemsetAsync(cnt, 0, (size_t)9 * N * 4, stream);  // cnt + cursor contiguous

    const int eb = (E + 255) / 256;
    const int sb = (threeN + 255) / 256;  // 1172 <= 2048

    degree_all<<<dim3(eb, 3), 256, 0, stream>>>(src[0], dst[0], src[1], dst[1], src[2], dst[2],
                                                cnt, N, E);
    rsqrt_kernel<<<(6 * N + 255) / 256, 256, 0, stream>>>(cnt, rs, 6 * N);

    scan_block<<<sb, 256, 0, stream>>>(cnt + threeN, off, aux, threeN);
    scan_aux2<<<1, 1024, 0, stream>>>(aux, sb);
    scan_add<<<sb, 256, 0, stream>>>(off, aux, threeN);
    fill_all<<<dim3(eb, 3), 256, 0, stream>>>(src[0], dst[0], src[1], dst[1], src[2], dst[2],
                                              off, cursor, srcs, N, E);

    const int gblocks = (N + BM - 1) / BM;
    const int ablocks = (int)(((size_t)N * 32 + 255) / 256);
    for (int r = 0; r < 3; ++r) {
        gemm_kernel<<<gblocks, 256, 0, stream>>>(x, W[r], y, N);
        const float* ro = rs + (size_t)r * N;            // out-deg rsqrt for relation r
        const float* ri = rs + (size_t)threeN + (size_t)r * N; // in-deg rsqrt
        if (r == 0)
            agg_kernel<0><<<ablocks, 256, 0, stream>>>(y, srcs, off, ro, ri, b[0], b[1], b[2],
                                                       out, N, r * N, threeN, Etot);
        else if (r == 1)
            agg_kernel<1><<<ablocks, 256, 0, stream>>>(y, srcs, off, ro, ri, b[0], b[1], b[2],
                                                       out, N, r * N, threeN, Etot);
        else
            agg_kernel<2><<<ablocks, 256, 0, stream>>>(y, srcs, off, ro, ri, b[0], b[1], b[2],
                                                       out, N, r * N, threeN, Etot);
    }
}

// Round 4
// 671.248 us; speedup vs baseline: 1.0494x; 1.0494x over previous
//
#include <hip/hip_runtime.h>
#include <hip/hip_bf16.h>

#define D 128
#define BM 64
#define BK 32
#define XS 66   // padded LDS stride for transposed x tile

__device__ __forceinline__ float bf2f(unsigned short v) {
    union { unsigned int u; float f; } t;
    t.u = ((unsigned int)v) << 16;
    return t.f;
}

// ---------------- degree count + in-degree rank: grid.y = relation ----------------
// cnt layout: [0,3N) out-degree by relation, [3N,6N) in-degree by relation.
// p[r*E+e] = rank of edge e within its (r, dst) bucket (from the atomic return).
__global__ void degree_rank_all(const int* __restrict__ s0, const int* __restrict__ d0,
                                const int* __restrict__ s1, const int* __restrict__ d1,
                                const int* __restrict__ s2, const int* __restrict__ d2,
                                int* __restrict__ cnt, int* __restrict__ p, int N, int E) {
    int r = blockIdx.y;
    const int* src = (r == 0) ? s0 : (r == 1) ? s1 : s2;
    const int* dst = (r == 0) ? d0 : (r == 1) ? d1 : d2;
    int i = blockIdx.x * blockDim.x + threadIdx.x;
    if (i < E) {
        atomicAdd(&cnt[(size_t)r * N + src[i]], 1);
        p[(size_t)r * E + i] = atomicAdd(&cnt[(size_t)3 * N + (size_t)r * N + dst[i]], 1);
    }
}

// ---------------- cnt(int) -> rsqrt(max(cnt,1)) ----------------
__global__ void rsqrt_kernel(const int* __restrict__ cnt, float* __restrict__ rs, int n) {
    int i = blockIdx.x * blockDim.x + threadIdx.x;
    if (i < n) rs[i] = rsqrtf(fmaxf((float)cnt[i], 1.0f));
}

// ---------------- exclusive scan over 3N: phase 1 (per-block) ----------------
__global__ void scan_block(const int* __restrict__ in, int* __restrict__ out,
                           int* __restrict__ aux, int n) {
    __shared__ int tmp[256];
    int tid = threadIdx.x;
    int gid = blockIdx.x * 256 + tid;
    int v = (gid < n) ? in[gid] : 0;
    tmp[tid] = v;
    __syncthreads();
    for (int o = 1; o < 256; o <<= 1) {
        int t = (tid >= o) ? tmp[tid - o] : 0;
        __syncthreads();
        tmp[tid] += t;
        __syncthreads();
    }
    if (gid < n) out[gid] = tmp[tid] - v;   // exclusive
    if (tid == 255) aux[blockIdx.x] = tmp[255];
}

// ---------------- scan phase 2: single block, 1024 thr, 2 elems/thread (nb<=2048) ----------------
__global__ void scan_aux2(int* __restrict__ aux, int nb) {
    __shared__ int tmp[1024];
    int tid = threadIdx.x;
    int i0 = 2 * tid, i1 = 2 * tid + 1;
    int v0 = (i0 < nb) ? aux[i0] : 0;
    int v1 = (i1 < nb) ? aux[i1] : 0;
    int s = v0 + v1;
    tmp[tid] = s;
    __syncthreads();
    for (int o = 1; o < 1024; o <<= 1) {
        int t = (tid >= o) ? tmp[tid - o] : 0;
        __syncthreads();
        tmp[tid] += t;
        __syncthreads();
    }
    int excl = tmp[tid] - s;
    if (i0 < nb) aux[i0] = excl;
    if (i1 < nb) aux[i1] = excl + v0;
}

// ---------------- scan phase 3 (add block offsets) ----------------
__global__ void scan_add(int* __restrict__ out, const int* __restrict__ aux, int n) {
    int gid = blockIdx.x * 256 + threadIdx.x;
    if (gid < n) out[gid] += aux[blockIdx.x];
}

// ---------------- CSR fill: atomic-free permutation write ----------------
__global__ void fill_perm(const int* __restrict__ s0, const int* __restrict__ d0,
                          const int* __restrict__ s1, const int* __restrict__ d1,
                          const int* __restrict__ s2, const int* __restrict__ d2,
                          const int* __restrict__ off, const int* __restrict__ p,
                          int* __restrict__ srcs, int N, int E) {
    int r = blockIdx.y;
    const int* src = (r == 0) ? s0 : (r == 1) ? s1 : s2;
    const int* dst = (r == 0) ? d0 : (r == 1) ? d1 : d2;
    int e = blockIdx.x * blockDim.x + threadIdx.x;
    if (e >= E) return;
    int d = dst[e];
    srcs[off[(size_t)r * N + d] + p[(size_t)r * E + e]] = src[e];
}

// ---------------- y = rs_out[row] * (x @ W)  (fp32 compute, bf16 store) ----------------
__global__ __launch_bounds__(256) void gemm_kernel(const float* __restrict__ x,
                                                   const float* __restrict__ W,
                                                   const float* __restrict__ rs_out,
                                                   __hip_bfloat16* __restrict__ y, int nrows) {
    __shared__ float xs[BK * XS];  // transposed x tile [k][row], stride 66
    __shared__ float ws[BK][D];    // W tile [k][col]

    const int tid = threadIdx.x;
    const int tx = tid & 31;
    const int ty = tid >> 5;
    const int row0 = blockIdx.x * BM;

    const int xr0 = tid >> 3;
    const int xk4 = tid & 7;
    const int wk0 = tid >> 5;
    const int wc4 = tid & 31;

    float acc[8][4];
#pragma unroll
    for (int i = 0; i < 8; ++i)
#pragma unroll
        for (int j = 0; j < 4; ++j) acc[i][j] = 0.f;

    float4 xv[2];
    float4 wv4[4];

#pragma unroll
    for (int l = 0; l < 2; ++l) {
        int grow = row0 + xr0 + l * 32;
        xv[l] = (grow < nrows) ? *(const float4*)(x + (size_t)grow * D + xk4 * 4)
                               : make_float4(0.f, 0.f, 0.f, 0.f);
    }
#pragma unroll
    for (int l = 0; l < 4; ++l)
        wv4[l] = *(const float4*)(W + (size_t)(wk0 + l * 8) * D + wc4 * 4);

    for (int kt = 0; kt < D; kt += BK) {
        __syncthreads();
#pragma unroll
        for (int l = 0; l < 2; ++l) {
            int r = xr0 + l * 32;
            xs[(xk4 * 4 + 0) * XS + r] = xv[l].x;
            xs[(xk4 * 4 + 1) * XS + r] = xv[l].y;
            xs[(xk4 * 4 + 2) * XS + r] = xv[l].z;
            xs[(xk4 * 4 + 3) * XS + r] = xv[l].w;
        }
#pragma unroll
        for (int l = 0; l < 4; ++l)
            *(float4*)&ws[wk0 + l * 8][wc4 * 4] = wv4[l];
        __syncthreads();
        if (kt + BK < D) {
            int ktn = kt + BK;
#pragma unroll
            for (int l = 0; l < 2; ++l) {
                int grow = row0 + xr0 + l * 32;
                xv[l] = (grow < nrows) ? *(const float4*)(x + (size_t)grow * D + ktn + xk4 * 4)
                                       : make_float4(0.f, 0.f, 0.f, 0.f);
            }
#pragma unroll
            for (int l = 0; l < 4; ++l)
                wv4[l] = *(const float4*)(W + (size_t)(ktn + wk0 + l * 8) * D + wc4 * 4);
        }
#pragma unroll
        for (int k = 0; k < BK; ++k) {
            float4 wv = *(const float4*)&ws[k][tx * 4];
            const float* xr = &xs[k * XS + ty * 8];
            float2 p0 = *(const float2*)(xr);
            float2 p1 = *(const float2*)(xr + 2);
            float2 p2 = *(const float2*)(xr + 4);
            float2 p3 = *(const float2*)(xr + 6);
            float xv8[8] = {p0.x, p0.y, p1.x, p1.y, p2.x, p2.y, p3.x, p3.y};
#pragma unroll
            for (int i = 0; i < 8; ++i) {
                acc[i][0] += xv8[i] * wv.x;
                acc[i][1] += xv8[i] * wv.y;
                acc[i][2] += xv8[i] * wv.z;
                acc[i][3] += xv8[i] * wv.w;
            }
        }
    }
#pragma unroll
    for (int i = 0; i < 8; ++i) {
        int grow = row0 + ty * 8 + i;
        if (grow < nrows) {
            float s = rs_out[grow];
            union { ushort4 u; __hip_bfloat16 h[4]; } pk;
            pk.h[0] = __float2bfloat16(acc[i][0] * s);
            pk.h[1] = __float2bfloat16(acc[i][1] * s);
            pk.h[2] = __float2bfloat16(acc[i][2] * s);
            pk.h[3] = __float2bfloat16(acc[i][3] * s);
            *(ushort4*)((unsigned short*)y + (size_t)grow * D + tx * 4) = pk.u;
        }
    }
}

// ---------------- gather-side aggregate: one 32-lane group per dst node ----------------
// y rows are pre-scaled by rs_out. MODE 0: out = acc*ri  1: += 2: relu(out+acc*ri+b)
template <int MODE>
__global__ __launch_bounds__(256) void agg_kernel(const __hip_bfloat16* __restrict__ y,
                                                  const int* __restrict__ srcs,
                                                  const int* __restrict__ off,
                                                  const float* __restrict__ rs_in,
                                                  const float* __restrict__ b0,
                                                  const float* __restrict__ b1,
                                                  const float* __restrict__ b2,
                                                  float* __restrict__ out,
                                                  int N, int rbase, int threeN, int Etot) {
    int gid  = blockIdx.x * blockDim.x + threadIdx.x;
    int node = gid >> 5;
    int lane = gid & 31;
    if (node >= N) return;
    int g = rbase + node;
    int j0 = off[g];
    int j1 = (g == threeN - 1) ? Etot : off[g + 1];

    float a0 = 0.f, a1 = 0.f, a2 = 0.f, a3 = 0.f;
    for (int j = j0; j < j1; ++j) {
        int s = srcs[j];
        ushort4 u = *(const ushort4*)((const unsigned short*)y + (size_t)s * D + lane * 4);
        a0 += bf2f(u.x);
        a1 += bf2f(u.y);
        a2 += bf2f(u.z);
        a3 += bf2f(u.w);
    }
    float ri = rs_in[node];
    float4 o = make_float4(a0 * ri, a1 * ri, a2 * ri, a3 * ri);
    float* orow = out + (size_t)node * D + lane * 4;
    if (MODE == 0) {
        *(float4*)orow = o;
    } else {
        float4 pv = *(const float4*)orow;
        o.x += pv.x; o.y += pv.y; o.z += pv.z; o.w += pv.w;
        if (MODE == 2) {
            int c0 = lane * 4;
            o.x = fmaxf(o.x + b0[c0 + 0] + b1[c0 + 0] + b2[c0 + 0], 0.f);
            o.y = fmaxf(o.y + b0[c0 + 1] + b1[c0 + 1] + b2[c0 + 1], 0.f);
            o.z = fmaxf(o.z + b0[c0 + 2] + b1[c0 + 2] + b2[c0 + 2], 0.f);
            o.w = fmaxf(o.w + b0[c0 + 3] + b1[c0 + 3] + b2[c0 + 3], 0.f);
        }
        *(float4*)orow = o;
    }
}

extern "C" void kernel_launch(void* const* d_in, const int* in_sizes, int n_in,
                              void* d_out, int out_size, void* d_ws, size_t ws_size,
                              hipStream_t stream) {
    const float* x = (const float*)d_in[0];
    const float* W[3]   = {(const float*)d_in[1], (const float*)d_in[5], (const float*)d_in[9]};
    const float* b[3]   = {(const float*)d_in[2], (const float*)d_in[6], (const float*)d_in[10]};
    const int*   src[3] = {(const int*)d_in[3],   (const int*)d_in[7],   (const int*)d_in[11]};
    const int*   dst[3] = {(const int*)d_in[4],   (const int*)d_in[8],   (const int*)d_in[12]};

    const int N = in_sizes[0] / D;
    const int E = in_sizes[3];
    const int threeN = 3 * N;
    const int Etot = 3 * E;
    float* out = (float*)d_out;

    // ws: [cnt 6N][rs 6N f][off 3N][aux 2048][p 3E][srcs 3E][y N*D bf16]  ~47 MB
    char* pp = (char*)d_ws;
    int* cnt    = (int*)pp;   pp += (size_t)6 * N * 4;
    float* rs   = (float*)pp; pp += (size_t)6 * N * 4;
    int* off    = (int*)pp;   pp += (size_t)3 * N * 4;
    int* aux    = (int*)pp;   pp += (size_t)2048 * 4;
    int* prank  = (int*)pp;   pp += (size_t)Etot * 4;
    int* srcs   = (int*)pp;   pp += (size_t)Etot * 4;
    pp = (char*)(((uintptr_t)pp + 15) & ~(uintptr_t)15);
    __hip_bfloat16* y = (__hip_bfloat16*)pp;

    hipMemsetAsync(cnt, 0, (size_t)6 * N * 4, stream);

    const int eb = (E + 255) / 256;
    const int sb = (threeN + 255) / 256;  // <= 2048

    degree_rank_all<<<dim3(eb, 3), 256, 0, stream>>>(src[0], dst[0], src[1], dst[1],
                                                     src[2], dst[2], cnt, prank, N, E);
    rsqrt_kernel<<<(6 * N + 255) / 256, 256, 0, stream>>>(cnt, rs, 6 * N);

    scan_block<<<sb, 256, 0, stream>>>(cnt + threeN, off, aux, threeN);
    scan_aux2<<<1, 1024, 0, stream>>>(aux, sb);
    scan_add<<<sb, 256, 0, stream>>>(off, aux, threeN);
    fill_perm<<<dim3(eb, 3), 256, 0, stream>>>(src[0], dst[0], src[1], dst[1], src[2], dst[2],
                                               off, prank, srcs, N, E);

    const int gblocks = (N + BM - 1) / BM;
    const int ablocks = (int)(((size_t)N * 32 + 255) / 256);
    for (int r = 0; r < 3; ++r) {
        const float* ro = rs + (size_t)r * N;
        const float* ri = rs + (size_t)threeN + (size_t)r * N;
        gemm_kernel<<<gblocks, 256, 0, stream>>>(x, W[r], ro, y, N);
        if (r == 0)
            agg_kernel<0><<<ablocks, 256, 0, stream>>>(y, srcs, off, ri, b[0], b[1], b[2],
                                                       out, N, r * N, threeN, Etot);
        else if (r == 1)
            agg_kernel<1><<<ablocks, 256, 0, stream>>>(y, srcs, off, ri, b[0], b[1], b[2],
                                                       out, N, r * N, threeN, Etot);
        else
            agg_kernel<2><<<ablocks, 256, 0, stream>>>(y, srcs, off, ri, b[0], b[1], b[2],
                                                       out, N, r * N, threeN, Etot);
    }
}